// Round 8
// baseline (160.348 us; speedup 1.0000x reference)
//
#include <hip/hip_runtime.h>

#define PHN 7
#define PWN 7
#define NB 49
#define SSCALE 0.0625f
#define CC 256
#define HH 200
#define WW 200
#define HWSZ (HH * WW)

#define CPG 4                     // channels per block = waves per block (CPW=1)
#define NSLOT 11                  // 16B slots per row: 11*16 = 176 B = row pitch
#define PITCHF 44                 // floats per raw tap row
#define REG_F 1280                // floats per channel region: 5 chunks x 1024 B
#define NR 4                      // rois per block, serial
#define MAXELEM 307               // valid (row,slot) elems: 28*11 - 1

// Staging load with NO VGPR destination: the register allocator cannot
// serialize it (v11-v14's 550cy-per-load chain). LDS write = uniform base
// + lane*16 (linear); rows pack at exactly 176 B so layout matches.
__device__ __forceinline__ void gload_lds16(const float* g, float* l) {
    __builtin_amdgcn_global_load_lds(
        (const __attribute__((address_space(1))) void*)g,
        (__attribute__((address_space(3))) void*)l, 16, 0, 0);
}

#define WAITV0 do { asm volatile("s_waitcnt vmcnt(0)" ::: "memory");   \
                    __builtin_amdgcn_sched_barrier(0); } while (0)
#define WAITLGKM0 do { asm volatile("s_waitcnt lgkmcnt(0)" ::: "memory"); \
                    __builtin_amdgcn_sched_barrier(0); } while (0)

__global__ __launch_bounds__(256, 8) void roi_align_v15(
    const float* __restrict__ features, const float* __restrict__ rois,
    float* __restrict__ out, int N)
{
    __shared__ float lds[CPG * REG_F];   // 20,480 B -> 8 blocks/CU (exact fit)

    // grid(8, N/NR, 8): blockIdx.x IS the xcd (linear round-robin).
    // cgroup = z*8 + x: each XCD sweeps all roi-chunks of one 4-channel
    // cgroup (1.28 MB slab, both batches) before the next -> L2-resident.
    const int xcd   = blockIdx.x;
    const int rbase = blockIdx.y * NR;
    const int cg    = blockIdx.z * 8 + xcd;

    const int t    = threadIdx.x;
    const int wid  = __builtin_amdgcn_readfirstlane(t >> 6);  // SGPR
    const int lane = t & 63;

    const int c  = cg * CPG + wid;       // this wave's channel (uniform)
    float*    tb = &lds[wid * REG_F];    // wave-private 5120 B region

    const int phl = lane / PWN;          // bin coords for compute (once)
    const int pwl = lane - phl * PWN;

    float x1, y1, bw, bh; int col0a, curN;
    const float* fb;
    float swx0[2], swx1[2], swy0[2], swy1[2]; int soA[2], scn;

#define DECODE(Q) {                                                          \
    int nb_ = rbase + (Q); if (nb_ > N - 1) nb_ = N - 1; curN = nb_;         \
    const float* r_ = rois + (size_t)nb_ * 5;                                \
    int   b_  = (int)r_[0];                                                  \
    x1 = r_[1] * SSCALE; y1 = r_[2] * SSCALE;                                \
    float x2_ = r_[3] * SSCALE, y2_ = r_[4] * SSCALE;                        \
    bw = fmaxf(x2_ - x1, 1.f) * (1.f / PWN);                                 \
    bh = fmaxf(y2_ - y1, 1.f) * (1.f / PHN);                                 \
    col0a = min((int)fmaxf(x1 + 0.25f * bw, 0.f), WW - 1) & ~3;              \
    fb = features + (size_t)(b_ * CC + c) * HWSZ; }

    // 5 chunks x 1024 B stage the 28 raw tap rows (elem = row*11 + slot).
    // All 64 lanes participate (full exec, as load_lds needs); lanes past
    // MAXELEM clamp to a valid source and land in the never-read pad.
#define GEOM_ISSUE() { _Pragma("unroll") for (int k_ = 0; k_ < 5; ++k_) {    \
    int elem_ = k_ * 64 + lane; if (elem_ > MAXELEM) elem_ = MAXELEM;        \
    int row_ = elem_ / NSLOT;            /* magic-mul */                     \
    int sl_  = elem_ - row_ * NSLOT;                                         \
    int s_   = row_ >> 1, tap_ = row_ & 1;                                   \
    float yb_ = (float)(s_ >> 1) + ((s_ & 1) ? 0.75f : 0.25f);               \
    float y_  = y1 + yb_ * bh;                                               \
    float cy_ = fmaxf(y_, 0.f);                                              \
    int   yl_ = min((int)cy_, HH - 1);                                       \
    int   gr_ = min(yl_ + tap_, HH - 1); /* hi-row clamp: dup row, wts ok */ \
    int   gc_ = min(col0a + (sl_ << 2), WW - 4);                             \
    gload_lds16(fb + gr_ * WW + gc_, &tb[k_ * 256]); } }

#define WSETUP() { _Pragma("unroll") for (int i = 0; i < 2; ++i) {           \
    float sf_ = i ? 0.75f : 0.25f;                                           \
    float x_  = x1 + ((float)pwl + sf_) * bw;                                \
    bool  vx_ = (x_ >= -1.f) && (x_ <= (float)WW);                           \
    float cx_ = fmaxf(x_, 0.f);                                              \
    int   xl_ = min((int)cx_, WW - 1);                                       \
    float fx_ = (xl_ >= WW - 1) ? 0.f : (cx_ - (float)xl_);                  \
    swx0[i] = vx_ ? (1.f - fx_) : 0.f;                                       \
    swx1[i] = vx_ ? fx_ : 0.f;                                               \
    soA[i]  = xl_ - col0a;               /* 0..41, +1 tap <= 43 < 44 */      \
    float yp_ = y1 + ((float)phl + sf_) * bh;                                \
    bool  vy_ = (yp_ >= -1.f) && (yp_ <= (float)HH);                         \
    float cyy_ = fmaxf(yp_, 0.f);                                            \
    int   yll_ = min((int)cyy_, HH - 1);                                     \
    float fyy_ = cyy_ - (float)yll_;     /* clamp dup-row: sum still ok */   \
    swy0[i] = vy_ ? (1.f - fyy_) : 0.f;                                      \
    swy1[i] = vy_ ? fyy_ : 0.f; }                                            \
    scn = curN; }

    // ---- prologue ----
    DECODE(0);
    GEOM_ISSUE();

    #pragma unroll
    for (int q = 0; q < NR; ++q) {
        WSETUP();                        // item q weights (pre-DECODE q+1)
        WAITV0;                          // staged rows landed in LDS

        // 16 taps, reduced per-iy to keep VGPR lean (static idx, rule #20)
        float acc = 0.f;
        if (lane < NB) {
            #pragma unroll
            for (int iy = 0; iy < 2; ++iy) {
                const float* plo = tb + (4 * phl + 2 * iy) * PITCHF;
                const float* phi = plo + PITCHF;
                float l0a = plo[soA[0]], l0b = plo[soA[0] + 1];
                float l1a = plo[soA[1]], l1b = plo[soA[1] + 1];
                float h0a = phi[soA[0]], h0b = phi[soA[0] + 1];
                float h1a = phi[soA[1]], h1b = phi[soA[1] + 1];
                float rlo = swx0[0] * l0a + swx1[0] * l0b
                          + swx0[1] * l1a + swx1[1] * l1b;
                float rhi = swx0[0] * h0a + swx1[0] * h0b
                          + swx0[1] * h1a + swx1[1] * h1b;
                acc += swy0[iy] * rlo + swy1[iy] * rhi;
            }
        }

        WAITLGKM0;                       // ds_reads COMPLETE: overwrite-safe
        if (q < NR - 1) {
            DECODE(q + 1);
            GEOM_ISSUE();                // next item's loads fly over store
        }
        if (lane < NB)
            out[(size_t)(scn * CC + c) * NB + lane] = acc * 0.25f;
    }
}

extern "C" void kernel_launch(void* const* d_in, const int* in_sizes, int n_in,
                              void* d_out, int out_size, void* d_ws, size_t ws_size,
                              hipStream_t stream) {
    const float* features = (const float*)d_in[0];
    const float* rois     = (const float*)d_in[1];
    float*       out      = (float*)d_out;

    int N = in_sizes[1] / 5;                 // 512 rois
    int chunks = (N + NR - 1) / NR;          // 128

    dim3 grid(8, chunks, CC / CPG / 8);      // (xcd, roi-chunk, cgroup-phase)
    roi_align_v15<<<grid, 256, 0, stream>>>(features, rois, out, N);
}

// Round 9
// 159.548 us; speedup vs baseline: 1.0050x; 1.0050x over previous
//
#include <hip/hip_runtime.h>

#define PHN 7
#define PWN 7
#define NB 49
#define SSCALE 0.0625f
#define CC 256
#define HH 200
#define WW 200
#define HWSZ (HH * WW)

#define CPG 8                     // channels per WAVE (sequential passes)
#define NSLOT 11                  // 16B slots per row: 11*16 = 176 B = row pitch
#define PITCHF 44                 // floats per raw tap row
#define REG_F 1280                // floats per wave region: 5 chunks x 1024 B
#define MAXELEM 307               // last valid (row,slot) elem: 28*11 - 1

// No-VGPR-destination staging load: allocator can't serialize it (v12-v14
// lesson), LDS write = uniform base + lane*16, rows pack at exactly 176 B.
__device__ __forceinline__ void gload_lds16(const float* g, float* l) {
    __builtin_amdgcn_global_load_lds(
        (const __attribute__((address_space(1))) void*)g,
        (__attribute__((address_space(3))) void*)l, 16, 0, 0);
}

#define WAITV0 do { asm volatile("s_waitcnt vmcnt(0)" ::: "memory");      \
                    __builtin_amdgcn_sched_barrier(0); } while (0)
#define WAITLGKM0 do { asm volatile("s_waitcnt lgkmcnt(0)" ::: "memory"); \
                    __builtin_amdgcn_sched_barrier(0); } while (0)

__global__ __launch_bounds__(256, 7) void roi_align_v16(
    const float* __restrict__ features, const float* __restrict__ rois,
    float* __restrict__ out, int N)
{
    __shared__ float lds[4 * REG_F];     // 20,480 B -> 7 blocks/CU = 28 waves

    // grid(8, N/4, 4): blockIdx.x IS the xcd (linear round-robin).
    // cgroup = z*8 + x: each XCD sweeps all roi-quads of one 8-channel
    // slab (2.56 MB incl both batches < 4 MB L2) before the next.
    const int xcd = blockIdx.x;
    const int cg  = blockIdx.z * 8 + xcd;            // 0..31
    const int c0  = cg * CPG;

    const int wid  = __builtin_amdgcn_readfirstlane(threadIdx.x >> 6);
    const int lane = threadIdx.x & 63;

    int roi = blockIdx.y * 4 + wid;                  // wave owns ONE roi
    if (roi > N - 1) roi = N - 1;                    // tail: benign dup write

    float* tb = &lds[wid * REG_F];                   // wave-private 5120 B

    // ---- roi decode: uniform per wave -> scalar ----
    const float* r = rois + (size_t)roi * 5;
    const int   b  = (int)r[0];
    const float x1 = r[1] * SSCALE, y1 = r[2] * SSCALE;
    const float x2 = r[3] * SSCALE, y2 = r[4] * SSCALE;
    const float bw = fmaxf(x2 - x1, 1.f) * (1.f / PWN);
    const float bh = fmaxf(y2 - y1, 1.f) * (1.f / PHN);
    const int col0a = min((int)fmaxf(x1 + 0.25f * bw, 0.f), WW - 1) & ~3;

    const float* fb = features + (size_t)(b * CC + c0) * HWSZ;

    // ---- hoisted per-lane source byte offsets: the ENTIRE staging
    //      geometry, computed once per wave, reused by all 8 channels ----
    int voff[5];
    #pragma unroll
    for (int k = 0; k < 5; ++k) {
        int elem = k * 64 + lane; if (elem > MAXELEM) elem = MAXELEM;
        int row = elem / NSLOT;              // magic-mul
        int sl  = elem - row * NSLOT;
        int s   = row >> 1, tap = row & 1;
        float yb = (float)(s >> 1) + ((s & 1) ? 0.75f : 0.25f);
        float y  = y1 + yb * bh;
        float cy = fmaxf(y, 0.f);
        int   yl = min((int)cy, HH - 1);
        int   gr = min(yl + tap, HH - 1);    // hi-row clamp: dup row, wts ok
        int   gc = min(col0a + (sl << 2), WW - 4);
        voff[k] = (gr * WW + gc) * 4;        // byte offset within channel
    }

    // ---- bin weights: once per wave (lane = bin) ----
    const int phl = lane / PWN;
    const int pwl = lane - phl * PWN;
    float swx0[2], swx1[2], swy0[2], swy1[2]; int soA[2];
    #pragma unroll
    for (int i = 0; i < 2; ++i) {
        float sf = i ? 0.75f : 0.25f;
        float x  = x1 + ((float)pwl + sf) * bw;
        bool  vx = (x >= -1.f) && (x <= (float)WW);
        float cx = fmaxf(x, 0.f);
        int   xl = min((int)cx, WW - 1);
        float fx = (xl >= WW - 1) ? 0.f : (cx - (float)xl);
        swx0[i] = vx ? (1.f - fx) : 0.f;
        swx1[i] = vx ? fx : 0.f;             // right edge: tap2 weight 0
        soA[i]  = xl - col0a;                // 0..41 (+1 tap <= 43 < 44)
        float yp = y1 + ((float)phl + sf) * bh;
        bool  vy = (yp >= -1.f) && (yp <= (float)HH);
        float cyy = fmaxf(yp, 0.f);
        int   yll = min((int)cyy, HH - 1);
        float fyy = cyy - (float)yll;        // clamp dup-row: sum still ok
        swy0[i] = vy ? (1.f - fyy) : 0.f;
        swy1[i] = vy ? fyy : 0.f;
    }

    // ---- prologue: stage channel 0 ----
    #pragma unroll
    for (int k = 0; k < 5; ++k)
        gload_lds16((const float*)((const char*)fb + voff[k]), tb + k * 256);

    // ---- 8 channel passes: ~15 issue + wait + ~50 compute instrs each ----
    #pragma unroll
    for (int ch = 0; ch < CPG; ++ch) {
        WAITV0;                              // staged rows landed in LDS

        float acc = 0.f;
        if (lane < NB) {
            #pragma unroll
            for (int iy = 0; iy < 2; ++iy) { // rows 4ph+2iy, +1 (s=2ph+iy)
                const float* plo = tb + (4 * phl + 2 * iy) * PITCHF;
                const float* phi = plo + PITCHF;
                float rlo = swx0[0] * plo[soA[0]] + swx1[0] * plo[soA[0] + 1]
                          + swx0[1] * plo[soA[1]] + swx1[1] * plo[soA[1] + 1];
                float rhi = swx0[0] * phi[soA[0]] + swx1[0] * phi[soA[0] + 1]
                          + swx0[1] * phi[soA[1]] + swx1[1] * phi[soA[1] + 1];
                acc += swy0[iy] * rlo + swy1[iy] * rhi;
            }
        }

        WAITLGKM0;                           // ds_reads done: overwrite-safe
        if (ch < CPG - 1) {                  // next channel: same voff, +HWSZ
            const char* fbn = (const char*)(fb + (size_t)(ch + 1) * HWSZ);
            #pragma unroll
            for (int k = 0; k < 5; ++k)
                gload_lds16((const float*)(fbn + voff[k]), tb + k * 256);
        }
        if (lane < NB)
            out[(size_t)(roi * CC + c0 + ch) * NB + lane] = acc * 0.25f;
    }
}

extern "C" void kernel_launch(void* const* d_in, const int* in_sizes, int n_in,
                              void* d_out, int out_size, void* d_ws, size_t ws_size,
                              hipStream_t stream) {
    const float* features = (const float*)d_in[0];
    const float* rois     = (const float*)d_in[1];
    float*       out      = (float*)d_out;

    int N = in_sizes[1] / 5;                 // 512 rois
    int quads = (N + 3) / 4;                 // 128 roi-quads (1 roi per wave)

    dim3 grid(8, quads, CC / CPG / 8);       // (xcd, roi-quad, cgroup-phase)
    roi_align_v16<<<grid, 256, 0, stream>>>(features, rois, out, N);
}